// Round 16
// baseline (150.311 us; speedup 1.0000x reference)
//
#include <hip/hip_runtime.h>

#define T_SEQ 2048
#define NH 4
#define DH 64

typedef __bf16 bf16x8 __attribute__((ext_vector_type(8)));
typedef float f32x4 __attribute__((ext_vector_type(4)));
typedef unsigned short u16x8 __attribute__((ext_vector_type(8)));

__device__ __forceinline__ unsigned short f2bf_rne(float x) {
  unsigned int u = __builtin_bit_cast(unsigned int, x);
  u += 0x7fffu + ((u >> 16) & 1u);
  return (unsigned short)(u >> 16);
}

__device__ __forceinline__ void async_cp16(const unsigned short* g, unsigned short* l) {
  __builtin_amdgcn_global_load_lds(
      (const __attribute__((address_space(1))) unsigned int*)g,
      (__attribute__((address_space(3))) unsigned int*)l, 16, 0, 0);
}

// ---------------------------------------------------------------------------
// wprep: W (256x256 fp32, [k][n]) -> Wt ([n][k] bf16, hi plane + lo plane).
// ---------------------------------------------------------------------------
__global__ __launch_bounds__(256) void wprep(const float* __restrict__ W,
                                             unsigned short* __restrict__ Wt) {
  int tid = blockIdx.x * 256 + threadIdx.x;  // 65536 elems
  int k = tid >> 8, n = tid & 255;
  float w = W[tid];
  unsigned int u = __builtin_bit_cast(unsigned int, w);
  Wt[n * 256 + k] = (unsigned short)(u >> 16);
  float lo = w - __builtin_bit_cast(float, u & 0xffff0000u);
  Wt[65536 + n * 256 + k] =
      (unsigned short)(__builtin_bit_cast(unsigned int, lo) >> 16);
}

// ---------------------------------------------------------------------------
// wh_gemm v3 (unchanged, known-good ~26us). 512 blocks x 32 rows, bf16 MFMA
// hi/lo split (D = AhBh + AhBl + AlBh).
// ---------------------------------------------------------------------------
__global__ __launch_bounds__(256, 2) void wh_gemm(
    const float* __restrict__ h, const unsigned short* __restrict__ Wt,
    unsigned short* __restrict__ Kb, unsigned short* __restrict__ Vt) {
  __shared__ __align__(16) unsigned short Ahi[32 * 256];  // [row][chunk^row&7]
  __shared__ __align__(16) unsigned short Alo[32 * 256];
  const int tid = threadIdx.x;
  const int wave = tid >> 6;
  const int lane = tid & 63;
  const int l15 = lane & 15;
  const int quad = lane >> 4;
  const int mbase = blockIdx.x * 32;  // 512 blocks
  const int col0 = wave * 64;         // one head per wave

  {
    const int r = tid >> 3;
    const int cbase = (tid & 7) * 4;
    const float4* hp = (const float4*)(h + ((size_t)(mbase + r) << 8) + cbase * 8);
#pragma unroll
    for (int j = 0; j < 4; j++) {
      float4 f0 = hp[2 * j];
      float4 f1 = hp[2 * j + 1];
      u16x8 hi, lo;
#define SPLIT1(v, idx)                                                    \
  {                                                                       \
    unsigned int u_ = __builtin_bit_cast(unsigned int, (v));              \
    hi[idx] = (unsigned short)(u_ >> 16);                                 \
    float r_ = (v) - __builtin_bit_cast(float, u_ & 0xffff0000u);         \
    lo[idx] = (unsigned short)(__builtin_bit_cast(unsigned int, r_) >> 16); \
  }
      SPLIT1(f0.x, 0) SPLIT1(f0.y, 1) SPLIT1(f0.z, 2) SPLIT1(f0.w, 3)
      SPLIT1(f1.x, 4) SPLIT1(f1.y, 5) SPLIT1(f1.z, 6) SPLIT1(f1.w, 7)
#undef SPLIT1
      const int chunk = (cbase + j) ^ (r & 7);
      *(u16x8*)&Ahi[r * 256 + chunk * 8] = hi;
      *(u16x8*)&Alo[r * 256 + chunk * 8] = lo;
    }
  }
  __syncthreads();

  f32x4 acc[2][4];
#pragma unroll
  for (int mt = 0; mt < 2; mt++)
#pragma unroll
    for (int nt = 0; nt < 4; nt++) acc[mt][nt] = (f32x4){0.f, 0.f, 0.f, 0.f};

#pragma unroll 2
  for (int ks = 0; ks < 8; ks++) {
    const int k0 = ks * 32 + quad * 8;
    bf16x8 ahi[2], alo[2];
#pragma unroll
    for (int mt = 0; mt < 2; mt++) {
      const int row = mt * 16 + l15;
      const int ch = (ks * 4 + quad) ^ (row & 7);
      ahi[mt] = *(const bf16x8*)&Ahi[row * 256 + ch * 8];
      alo[mt] = *(const bf16x8*)&Alo[row * 256 + ch * 8];
    }
#pragma unroll
    for (int nt = 0; nt < 4; nt++) {
      const unsigned short* wp = Wt + ((size_t)(col0 + nt * 16 + l15) << 8) + k0;
      bf16x8 bhi = *(const bf16x8*)wp;
      bf16x8 blo = *(const bf16x8*)(wp + 65536);
#pragma unroll
      for (int mt = 0; mt < 2; mt++) {
        acc[mt][nt] = __builtin_amdgcn_mfma_f32_16x16x32_bf16(ahi[mt], bhi, acc[mt][nt], 0, 0, 0);
        acc[mt][nt] = __builtin_amdgcn_mfma_f32_16x16x32_bf16(alo[mt], bhi, acc[mt][nt], 0, 0, 0);
        acc[mt][nt] = __builtin_amdgcn_mfma_f32_16x16x32_bf16(ahi[mt], blo, acc[mt][nt], 0, 0, 0);
      }
    }
  }

  const float s1 = 0.424664717f;  // sqrt(log2(e)/8)
#pragma unroll
  for (int mt = 0; mt < 2; mt++) {
    int row = mbase + mt * 16 + quad * 4;
    int b = row >> 11;
    int tb = row & 2047;
    size_t bh = (size_t)(b * NH + wave);
#pragma unroll
    for (int nt = 0; nt < 4; nt++) {
      int d = nt * 16 + l15;
      Kb[(bh * T_SEQ + tb + 0) * DH + d] = f2bf_rne(acc[mt][nt][0] * s1);
      Kb[(bh * T_SEQ + tb + 1) * DH + d] = f2bf_rne(acc[mt][nt][1] * s1);
      Kb[(bh * T_SEQ + tb + 2) * DH + d] = f2bf_rne(acc[mt][nt][2] * s1);
      Kb[(bh * T_SEQ + tb + 3) * DH + d] = f2bf_rne(acc[mt][nt][3] * s1);
      ushort4 vp;
      vp.x = f2bf_rne(acc[mt][nt][0]);
      vp.y = f2bf_rne(acc[mt][nt][1]);
      vp.z = f2bf_rne(acc[mt][nt][2]);
      vp.w = f2bf_rne(acc[mt][nt][3]);
      *(ushort4*)&Vt[(bh * DH + d) * T_SEQ + tb] = vp;
    }
  }
}

// ---------------------------------------------------------------------------
// attn v4: software-pipelined phases (T15). Iter t runs QKT(t) [MFMA] then
// softmax(t-1)+PV(t-1) [VALU+MFMA] -- sfr(t) consumed only at t+1, so the
// scheduler interleaves both pipes (prev structure serialized QKT->softmax->PV
// within each iter: MfmaUtil 20% + VALUBusy 38%, time invariant to occupancy
// and LDS traffic => dependency-chain-bound, not throughput-bound).
// K double-buffered; V TRIPLE-buffered (PV(t-1) reads V[(t-1)%3] while
// stage(t+1) writes V[(t+1)%3]). sfrA/sfrB named sets, 2x unroll (rule #20).
// LDS 56KB -> 2 blocks/CU (occupancy proven irrelevant rounds 9-11).
// ---------------------------------------------------------------------------
__global__ __launch_bounds__(256, 2) void attn(
    const unsigned short* __restrict__ Kb, const unsigned short* __restrict__ Vt,
    float* __restrict__ out) {
  __shared__ __align__(16) unsigned short ldsK[2 * 4096];  // [t&1][key][swz]
  __shared__ __align__(16) unsigned short ldsV[3 * 4096];  // [t%3][d][swz]
  __shared__ __align__(16) unsigned short ldsP[4][2048];   // per-wave P
  const int tid = threadIdx.x;
  const int wave = tid >> 6;
  const int lane = tid & 63;
  const int l15 = lane & 15;
  const int quad = lane >> 4;
  const int lbid = (blockIdx.x & 7) * 64 + (blockIdx.x >> 3);  // 512 = 8*64
  const int bh = lbid >> 4;
  const int qtile = lbid & 15;
  const unsigned short* Kbh = Kb + (size_t)bh * T_SEQ * DH;
  const unsigned short* Vbh = Vt + (size_t)bh * DH * T_SEQ;

  const int qbase = qtile * 128 + wave * 32;
  bf16x8 aq[2][2];
#pragma unroll
  for (int mt = 0; mt < 2; mt++) {
    const unsigned short* qp = &Kbh[(qbase + mt * 16 + l15) * DH + quad * 8];
    aq[mt][0] = *(const bf16x8*)qp;
    aq[mt][1] = *(const bf16x8*)(qp + 32);
  }

  f32x4 o[2][4];
  float lsum[2][4];
#pragma unroll
  for (int mt = 0; mt < 2; mt++)
#pragma unroll
    for (int i = 0; i < 4; i++) {
      o[mt][i] = (f32x4){0.f, 0.f, 0.f, 0.f};
      lsum[mt][i] = 0.f;
    }
  unsigned short* Pw = ldsP[wave];

  auto stage = [&](int t) {
    unsigned short* kb = ldsK + (t & 1) * 4096;
    unsigned short* vb = ldsV + (t % 3) * 4096;
#pragma unroll
    for (int i = 0; i < 2; i++) {
      int slot = i * 256 + tid;
      int r = slot >> 3;
      int c = (slot & 7) ^ (r & 7);
      async_cp16(&Kbh[(t * 64 + r) * DH + c * 8], kb + (i * 256 + wave * 64) * 8);
      async_cp16(&Vbh[(size_t)r * T_SEQ + t * 64 + c * 8], vb + (i * 256 + wave * 64) * 8);
    }
  };

  auto qkt = [&](int t, f32x4 (&sfr)[2][4]) {
    const unsigned short* Kl = ldsK + (t & 1) * 4096;
    __builtin_amdgcn_s_setprio(1);
#pragma unroll
    for (int nt = 0; nt < 4; nt++) {
      int key = nt * 16 + l15;
      bf16x8 kf0 = *(const bf16x8*)&Kl[key * 64 + ((quad ^ (key & 7)) << 3)];
      bf16x8 kf1 = *(const bf16x8*)&Kl[key * 64 + (((4 + quad) ^ (key & 7)) << 3)];
#pragma unroll
      for (int mt = 0; mt < 2; mt++) {
        f32x4 s = {0.f, 0.f, 0.f, 0.f};
        s = __builtin_amdgcn_mfma_f32_16x16x32_bf16(aq[mt][0], kf0, s, 0, 0, 0);
        s = __builtin_amdgcn_mfma_f32_16x16x32_bf16(aq[mt][1], kf1, s, 0, 0, 0);
        sfr[mt][nt] = s;
      }
    }
    __builtin_amdgcn_s_setprio(0);
  };

  auto softmax = [&](f32x4 (&sfr)[2][4]) {
#pragma unroll
    for (int mt = 0; mt < 2; mt++)
#pragma unroll
      for (int nt = 0; nt < 4; nt++) {
        int col = nt * 16 + l15;
#pragma unroll
        for (int reg = 0; reg < 4; reg++) {
          float v = sfr[mt][nt][reg];
          float e = __builtin_amdgcn_exp2f(fmaxf(v, 0.2f * v));
          lsum[mt][reg] += e;
          int row = mt * 16 + quad * 4 + reg;
          Pw[(row << 6) + (((((col >> 3) ^ (row & 7))) << 3) | (col & 7))] =
              (unsigned short)(__builtin_bit_cast(unsigned int, e) >> 16);
        }
      }
  };

  auto pv = [&](int t) {
    const unsigned short* Vl = ldsV + (t % 3) * 4096;
    __builtin_amdgcn_s_setprio(1);
#pragma unroll
    for (int kc = 0; kc < 2; kc++) {
      const int pch = (((kc << 2) + quad) ^ (l15 & 7)) << 3;
      bf16x8 ap0 = *(const bf16x8*)&Pw[(l15 << 6) + pch];
      bf16x8 ap1 = *(const bf16x8*)&Pw[((16 + l15) << 6) + pch];
#pragma unroll
      for (int nt = 0; nt < 4; nt++) {
        int d = nt * 16 + l15;
        bf16x8 vf = *(const bf16x8*)&Vl[(d << 6) + ((((kc << 2) + quad) ^ (d & 7)) << 3)];
        o[0][nt] = __builtin_amdgcn_mfma_f32_16x16x32_bf16(ap0, vf, o[0][nt], 0, 0, 0);
        o[1][nt] = __builtin_amdgcn_mfma_f32_16x16x32_bf16(ap1, vf, o[1][nt], 0, 0, 0);
      }
    }
    __builtin_amdgcn_s_setprio(0);
  };

  f32x4 sfrA[2][4], sfrB[2][4];

  // prologue: tiles 0 and 1 in flight; QKT(0)
  stage(0);
  stage(1);
  asm volatile("s_waitcnt vmcnt(4)" ::: "memory");  // tile 0 landed
  __builtin_amdgcn_s_barrier();
  __builtin_amdgcn_sched_barrier(0);
  qkt(0, sfrB);

  auto step = [&](int t, f32x4 (&sn)[2][4], f32x4 (&so)[2][4], bool has_next) {
    if (has_next) {
      stage(t + 1);
      asm volatile("s_waitcnt vmcnt(4)" ::: "memory");  // tile t landed
    } else {
      asm volatile("s_waitcnt vmcnt(0)" ::: "memory");
    }
    __builtin_amdgcn_s_barrier();
    __builtin_amdgcn_sched_barrier(0);
    if (t <= 31) qkt(t, sn);          // MFMA pipe; sn unused until t+1
    softmax(so);                      // VALU pipe, independent -> interleaves
    __builtin_amdgcn_s_waitcnt(0xC07F);  // lgkmcnt(0): P writes landed
    pv(t - 1);                        // V[(t-1)%3] safe: overwriter stages t+2
    __builtin_amdgcn_sched_barrier(0);
    __builtin_amdgcn_s_barrier();     // all reads done before next stage
  };

  for (int it = 1; it < 31; it += 2) {
    step(it, sfrA, sfrB, true);
    step(it + 1, sfrB, sfrA, true);
  }
  step(31, sfrA, sfrB, false);
  step(32, sfrB, sfrA, false);

  // epilogue
  const int b = bh >> 2, head = bh & 3;
#pragma unroll
  for (int mt = 0; mt < 2; mt++) {
    float inv[4];
#pragma unroll
    for (int reg = 0; reg < 4; reg++) {
      float l = lsum[mt][reg];
      l += __shfl_xor(l, 1, 64);
      l += __shfl_xor(l, 2, 64);
      l += __shfl_xor(l, 4, 64);
      l += __shfl_xor(l, 8, 64);
      inv[reg] = 1.0f / l;
    }
#pragma unroll
    for (int nt = 0; nt < 4; nt++) {
      int d = nt * 16 + l15;
#pragma unroll
      for (int reg = 0; reg < 4; reg++) {
        int trow = qbase + mt * 16 + quad * 4 + reg;
        out[((size_t)b * T_SEQ + trow) * 256 + head * 64 + d] = o[mt][nt][reg] * inv[reg];
      }
    }
  }
}

extern "C" void kernel_launch(void* const* d_in, const int* in_sizes, int n_in,
                              void* d_out, int out_size, void* d_ws, size_t ws_size,
                              hipStream_t stream) {
  const float* h = (const float*)d_in[0];
  const float* W = (const float*)d_in[1];
  float* out = (float*)d_out;
  // workspace: Kb 8 MB + Vt 8 MB + Wt 256 KB
  unsigned short* Kb = (unsigned short*)d_ws;
  unsigned short* Vt = Kb + (size_t)32 * T_SEQ * DH;
  unsigned short* Wt = Vt + (size_t)32 * T_SEQ * DH;
  wprep<<<256, 256, 0, stream>>>(W, Wt);
  wh_gemm<<<512, 256, 0, stream>>>(h, Wt, Kb, Vt);
  attn<<<512, 256, 0, stream>>>(Kb, Vt, out);
}